// Round 1
// baseline (1398.631 us; speedup 1.0000x reference)
//
#include <hip/hip_runtime.h>

// Problem constants (from reference)
#define BSL 16
#define NT  8000
#define DF  2048
#define HH  128
#define MROWS (BSL * NT)        // 128000
#define KT_N  (DF / 32)         // 64 k-chunks of 32

typedef __attribute__((ext_vector_type(8))) short short8;
typedef __attribute__((ext_vector_type(4))) float f32x4;
typedef __attribute__((ext_vector_type(4))) unsigned int u32x4;

static __device__ __forceinline__ short f2bf(float f) {
    unsigned u = __float_as_uint(f);
    u += 0x7fffu + ((u >> 16) & 1u);   // round-to-nearest-even
    return (short)(u >> 16);
}

// Single-instruction packed f32->bf16 (RNE), replaces ~12 VALU ops per pair.
static __device__ __forceinline__ unsigned cvt_pk_bf16(float lo, float hi) {
    unsigned r;
    asm("v_cvt_pk_bf16_f32 %0, %1, %2" : "=v"(r) : "v"(lo), "v"(hi));
    return r;
}

static __device__ __forceinline__ float sigmoidf_fast(float x) {
    return 1.0f / (1.0f + __expf(-x));
}

// Async global->LDS, 16B per lane (global_load_lds_dwordx4).
// LDS dest semantics: wave-uniform base (lane0's pointer) + lane*16.
static __device__ __forceinline__ void async16(const void* g, void* l) {
    __builtin_amdgcn_global_load_lds(
        (const __attribute__((address_space(1))) unsigned int*)g,
        (__attribute__((address_space(3))) unsigned int*)l, 16, 0, 0);
}

// ---------------------------------------------------------------------------
// Pack W1 [2048][128] fp32 -> bf16 in MFMA B-fragment order:
// bpack[((kt*8+ct)*64 + lane)*8 + j] = bf16(W1[kt*32 + (lane>>4)*8 + j][ct*16 + (lane&15)])
// Per-kt tile is contiguous: 8192 B at byte offset kt*8192.
// ---------------------------------------------------------------------------
__global__ void pack_w1_kernel(const float* __restrict__ W1, short* __restrict__ bpack)
{
    int idx = blockIdx.x * 256 + threadIdx.x;       // 0 .. 64*8*64
    if (idx >= KT_N * 8 * 64) return;
    int lane = idx & 63;
    int ct   = (idx >> 6) & 7;
    int kt   = idx >> 9;
    int quad = lane >> 4, l16 = lane & 15;
    short8 v;
#pragma unroll
    for (int j = 0; j < 8; ++j) {
        int k = kt * 32 + quad * 8 + j;
        int h = ct * 16 + l16;
        v[j] = f2bf(W1[k * HH + h]);
    }
    *(short8*)(bpack + (long)idx * 8) = v;
}

// ---------------------------------------------------------------------------
// Detect mask dtype: bool(1B) vs int32(4B) upload. A nonzero byte at
// offset%4 != 0 within the first 128000 bytes <=> bool layout.
// Vectorized uint4 scan (no dependent early-exit chain).
// ---------------------------------------------------------------------------
__global__ void detect_mask_kernel(const uint4* __restrict__ m4, int* __restrict__ flag)
{
    __shared__ int any;
    if (threadIdx.x == 0) any = 0;
    __syncthreads();
    unsigned acc = 0;
    for (int i = threadIdx.x; i < MROWS / 16; i += 256) {   // 8000 uint4 = 128000 B
        uint4 v = m4[i];
        acc |= v.x | v.y | v.z | v.w;
    }
    if (acc & 0xFFFFFF00u) atomicOr(&any, 1);   // nonzero upper bytes => bool bytes
    __syncthreads();
    if (threadIdx.x == 0) *flag = any;          // 1 = bool bytes, 0 = int32
}

// ---------------------------------------------------------------------------
// Fused tiles-MLP GEMM: scores[r] = sigmoid(feats[r,:] @ W1 + b1) @ W2 + b2
// Block = 256 thr = 4 waves; wave = 64 rows x 128 cols; grid = 500 blocks
// (exactly 2 blocks/CU resident). B tile (8 KB/kt) staged per-BLOCK into
// double-buffered LDS via global_load_lds; A direct from global fp32,
// converted in-register with v_cvt_pk_bf16_f32. One barrier per kt paces
// all waves so the LDS B tile is shared (B global traffic: 2 GB -> 256 MB).
// ---------------------------------------------------------------------------
__global__ __launch_bounds__(256, 2)
void gemm1_kernel(const float* __restrict__ feats, const short* __restrict__ bpack,
                  const float* __restrict__ b1, const float* __restrict__ W2,
                  const float* __restrict__ b2, float* __restrict__ scores)
{
    __shared__ __align__(16) short ldsB[2][4096];   // 2 x 8 KB, linear (matches stage order)

    const int lane = threadIdx.x & 63;
    const int wave = threadIdx.x >> 6;
    const int quad = lane >> 4;
    const int l16  = lane & 15;
    const long row0 = (long)blockIdx.x * 256 + wave * 64;

    f32x4 acc[4][8];
#pragma unroll
    for (int rt = 0; rt < 4; ++rt)
#pragma unroll
        for (int ct = 0; ct < 8; ++ct)
            acc[rt][ct] = (f32x4){0.f, 0.f, 0.f, 0.f};

    float b1v[8], w2v[8];
#pragma unroll
    for (int ct = 0; ct < 8; ++ct) {
        b1v[ct] = b1[ct * 16 + l16];
        w2v[ct] = W2[ct * 16 + l16];
    }

    // Staging addresses: each wave stages 1 KB per 4-KB half (2 calls/wave).
    const char* gB = (const char*)bpack + wave * 1024 + lane * 16;
    char* lB0 = (char*)&ldsB[0][0] + wave * 1024 + lane * 16;
    char* lB1 = (char*)&ldsB[1][0] + wave * 1024 + lane * 16;

    // Prologue: stage kt=0 into buf0.
    async16(gB, lB0);
    async16(gB + 4096, lB0 + 4096);

    const float* a_base = feats + (row0 + l16) * (long)DF + quad * 8;

#pragma unroll 1
    for (int kt = 0; kt < KT_N; ++kt) {
        const int cur = kt & 1;
        // Drains vmcnt: stage(kt) complete; all waves done reading buf[cur^1].
        __syncthreads();
        if (kt + 1 < KT_N) {
            const char* g = gB + (kt + 1) * 8192;
            char* l = cur ? lB0 : lB1;
            async16(g, l);
            async16(g + 4096, l + 4096);
        }

        // A: 4 row-tiles x 8 floats/lane, fp32 -> packed bf16 in-register.
        short8 afrag[4];
#pragma unroll
        for (int rt = 0; rt < 4; ++rt) {
            const float4* p = (const float4*)(a_base + rt * (16 * DF) + kt * 32);
            float4 x0 = p[0], x1 = p[1];
            u32x4 u;
            u[0] = cvt_pk_bf16(x0.x, x0.y);
            u[1] = cvt_pk_bf16(x0.z, x0.w);
            u[2] = cvt_pk_bf16(x1.x, x1.y);
            u[3] = cvt_pk_bf16(x1.z, x1.w);
            afrag[rt] = __builtin_bit_cast(short8, u);
        }

        const short* bb = &ldsB[cur][0];
#pragma unroll
        for (int ct = 0; ct < 8; ++ct) {
            short8 bfrag = *(const short8*)(bb + ct * 512 + lane * 8);  // ds_read_b128, conflict-free
#pragma unroll
            for (int rt = 0; rt < 4; ++rt)
                acc[rt][ct] = __builtin_amdgcn_mfma_f32_16x16x32_bf16(afrag[rt], bfrag, acc[rt][ct], 0, 0, 0);
        }
    }

    // Epilogue: score = sum_h sigmoid(h + b1[h]) * W2[h] + b2
    // C layout: col = ct*16 + l16, row = rt*16 + quad*4 + r
    const float b2s = b2[0];
#pragma unroll
    for (int rt = 0; rt < 4; ++rt) {
        float part[4] = {0.f, 0.f, 0.f, 0.f};
#pragma unroll
        for (int ct = 0; ct < 8; ++ct) {
#pragma unroll
            for (int r = 0; r < 4; ++r) {
                float s = sigmoidf_fast(acc[rt][ct][r] + b1v[ct]);
                part[r] += s * w2v[ct];
            }
        }
#pragma unroll
        for (int r = 0; r < 4; ++r) {
            float p = part[r];
            p += __shfl_xor(p, 1, 64);
            p += __shfl_xor(p, 2, 64);
            p += __shfl_xor(p, 4, 64);
            p += __shfl_xor(p, 8, 64);
            if (l16 == 0) scores[row0 + rt * 16 + quad * 4 + r] = p + b2s;
        }
    }
}

// ---------------------------------------------------------------------------
// Per-slide: bitonic sort 8192 keys (masked/pad -> +inf) ascending, extract
// top-100 (desc) + bottom-100 (asc), then fused prediction MLP (fp32).
// out[0..15] = y, out[16 + b*200 + j] = extreme scores.
// ---------------------------------------------------------------------------
__global__ __launch_bounds__(1024)
void sort_mlp_kernel(const float* __restrict__ scores, const void* __restrict__ maskp,
                     const int* __restrict__ flag,
                     const float* __restrict__ Wm1, const float* __restrict__ bm1,
                     const float* __restrict__ Wm2, const float* __restrict__ bm2,
                     const float* __restrict__ Wm3, const float* __restrict__ bm3,
                     float* __restrict__ out)
{
    __shared__ float key[8192];
    __shared__ float ext[200];
    __shared__ float g1[128];
    __shared__ float g2[64];
    __shared__ int s_cnt;

    const int b = blockIdx.x;
    const int t = threadIdx.x;
    const bool isbyte = (*flag != 0);
    const unsigned char* mb = (const unsigned char*)maskp;
    const int* mi = (const int*)maskp;

    if (t == 0) s_cnt = 0;
    __syncthreads();

    int local = 0;
    for (int i = t; i < 8192; i += 1024) {
        float v = __builtin_inff();
        if (i < NT) {
            int gi = b * NT + i;
            bool masked = isbyte ? (mb[gi] != 0) : (mi[gi] != 0);
            if (!masked) { v = scores[gi]; ++local; }
        }
        key[i] = v;
    }
    if (local) atomicAdd(&s_cnt, local);
    __syncthreads();
    const int V = s_cnt;   // valid (unmasked) count, ~5600 >> 200

    // Bitonic sort ascending over 8192 elements
    for (int k = 2; k <= 8192; k <<= 1) {
        for (int j = k >> 1; j > 0; j >>= 1) {
            for (int c = t; c < 4096; c += 1024) {
                int i = ((c & ~(j - 1)) << 1) | (c & (j - 1));
                int p = i | j;
                float a = key[i], bb = key[p];
                bool up = ((i & k) == 0);
                bool sw = up ? (a > bb) : (a < bb);
                if (sw) { key[i] = bb; key[p] = a; }
            }
            __syncthreads();
        }
    }

    // extreme = [top-100 desc, bottom-100 asc]
    if (t < 200) {
        float v = (t < 100) ? key[V - 1 - t] : key[t - 100];
        ext[t] = v;
        out[16 + b * 200 + t] = v;
    }
    __syncthreads();

    // MLP: 200 -> 128 -> 64 -> 1 (fp32)
    if (t < 128) {
        float s = bm1[t];
        for (int j = 0; j < 200; ++j) s += ext[j] * Wm1[j * 128 + t];
        g1[t] = sigmoidf_fast(s);
    }
    __syncthreads();
    if (t < 64) {
        float s = bm2[t];
        for (int j = 0; j < 128; ++j) s += g1[j] * Wm2[j * 64 + t];
        g2[t] = sigmoidf_fast(s);
    }
    __syncthreads();
    if (t < 64) {
        float p = g2[t] * Wm3[t];
        p += __shfl_xor(p, 1, 64);
        p += __shfl_xor(p, 2, 64);
        p += __shfl_xor(p, 4, 64);
        p += __shfl_xor(p, 8, 64);
        p += __shfl_xor(p, 16, 64);
        p += __shfl_xor(p, 32, 64);
        if (t == 0) out[b] = p + bm3[0];
    }
}

extern "C" void kernel_launch(void* const* d_in, const int* in_sizes, int n_in,
                              void* d_out, int out_size, void* d_ws, size_t ws_size,
                              hipStream_t stream)
{
    const float* feats = (const float*)d_in[0];
    const void*  maskp = d_in[1];
    const float* W1  = (const float*)d_in[2];
    const float* b1  = (const float*)d_in[3];
    const float* W2  = (const float*)d_in[4];
    const float* b2  = (const float*)d_in[5];
    const float* Wm1 = (const float*)d_in[6];
    const float* bm1 = (const float*)d_in[7];
    const float* Wm2 = (const float*)d_in[8];
    const float* bm2 = (const float*)d_in[9];
    const float* Wm3 = (const float*)d_in[10];
    const float* bm3 = (const float*)d_in[11];
    float* out = (float*)d_out;

    char* ws = (char*)d_ws;
    short* bpack  = (short*)ws;                          // 524288 B (bf16 packed W1)
    float* scores = (float*)(ws + 524288);               // 512000 B
    int*   flag   = (int*)(ws + 524288 + 512000);        // 4 B

    hipLaunchKernelGGL(pack_w1_kernel, dim3(128), dim3(256), 0, stream, W1, bpack);
    hipLaunchKernelGGL(detect_mask_kernel, dim3(1), dim3(256), 0, stream,
                       (const uint4*)maskp, flag);
    hipLaunchKernelGGL(gemm1_kernel, dim3(500), dim3(256), 0, stream,
                       feats, bpack, b1, W2, b2, scores);
    hipLaunchKernelGGL(sort_mlp_kernel, dim3(16), dim3(1024), 0, stream,
                       scores, maskp, flag, Wm1, bm1, Wm2, bm2, Wm3, bm3, out);
}